// Round 5
// baseline (270.266 us; speedup 1.0000x reference)
//
#include <hip/hip_runtime.h>
#include <hip/hip_bf16.h>
#include <stdint.h>

#define NTOK 4096
#define DIM  256
#define NH   8
#define HD   32
#define KSPLIT 4     // waves per attention block (K-dim split)
#define QTILE 32     // q-rows per block

typedef __attribute__((ext_vector_type(8))) short short8;
typedef __attribute__((ext_vector_type(4))) short short4v;
typedef __attribute__((ext_vector_type(4))) float float4v;
typedef unsigned short u16;
typedef unsigned int u32;

__device__ __forceinline__ u16 f2bf(float f) {        // RNE (cold paths)
    union { float f; u32 u; } c; c.f = f;
    u32 u = c.u;
    u = u + 0x7FFFu + ((u >> 16) & 1u);
    return (u16)(u >> 16);
}
__device__ __forceinline__ u16 f2bf_fast(float f) {   // round-half-up (hot path)
    union { float f; u32 u; } c; c.f = f;
    return (u16)((c.u + 0x8000u) >> 16);
}

// ---------------- kernel A: x (f32) -> bf16 ----------------
__global__ void x_to_bf16(const float* __restrict__ x, u16* __restrict__ xb) {
    int i = (blockIdx.x * blockDim.x + threadIdx.x) * 4;
    float4 v = *(const float4*)(x + i);
    ushort4 o;
    o.x = f2bf(v.x); o.y = f2bf(v.y); o.z = f2bf(v.z); o.w = f2bf(v.w);
    *(ushort4*)(xb + i) = o;
}

// ---------------- kernel 0: transpose weights (f32 256x256 -> bf16 WT) ----------------
__global__ void transpose_w(const float* __restrict__ Wq, const float* __restrict__ Wk,
                            const float* __restrict__ Wv, const float* __restrict__ Wo,
                            u16* __restrict__ WT) {
    const float* srcs[4] = {Wq, Wk, Wv, Wo};
    const float* W = srcs[blockIdx.y];
    int o = blockIdx.x, i = threadIdx.x;
    WT[blockIdx.y * 65536 + o * 256 + i] = f2bf(W[i * 256 + o]);
}

// ---------------- kernel 1: adj (f32 0/1) -> bitmask via ballot ----------------
__global__ __launch_bounds__(256) void adj_to_bits(const float* __restrict__ adj,
                                                   u32* __restrict__ bits) {
    size_t i = (size_t)blockIdx.x * 256 + threadIdx.x;
    float v = adj[i];
    unsigned long long b = __ballot(v != 0.0f);
    int lane = threadIdx.x & 63;
    if (lane == 0)       bits[i >> 5] = (u32)b;
    else if (lane == 32) bits[i >> 5] = (u32)(b >> 32);
}

// ---------------- kernel 2: QKV projection ----------------
// mat 0 -> Q[m][n] (pre-scaled by 1/sqrt(HD)*log2e), mat 1 -> K[m][n]
// mat 2 -> VT[n][m] via swapped operands: D[n][m] in C-layout -> coalesced store
__global__ __launch_bounds__(64) void qkv_gemm(
    const u16* __restrict__ xb,
    const u16* __restrict__ WT,
    const float* __restrict__ bq, const float* __restrict__ bk, const float* __restrict__ bv,
    u16* __restrict__ Q, u16* __restrict__ K, u16* __restrict__ VT) {
    int lane = threadIdx.x, quad = lane >> 4, l16 = lane & 15;
    int mtile = blockIdx.x, ntile = blockIdx.y, mat = blockIdx.z;
    const float* bias = (mat == 0) ? bq : (mat == 1) ? bk : bv;
    const u16* xrow = xb + (size_t)(mtile * 16 + l16) * DIM + quad * 8;
    const u16* wrow = WT + (size_t)mat * 65536 + (size_t)(ntile * 16 + l16) * DIM + quad * 8;
    const u16* arow = (mat == 2) ? wrow : xrow;   // mat 2: A=W^T rows (n), B=x rows (m)
    const u16* brow = (mat == 2) ? xrow : wrow;
    float4v acc = {0.f, 0.f, 0.f, 0.f};
#pragma unroll
    for (int k0 = 0; k0 < DIM; k0 += 32) {
        short8 af = *(const short8*)(arow + k0);
        short8 bf = *(const short8*)(brow + k0);
        acc = __builtin_amdgcn_mfma_f32_16x16x32_bf16(af, bf, acc, 0, 0, 0);
    }
    if (mat == 2) {
#pragma unroll
        for (int r = 0; r < 4; ++r) {
            int n = ntile * 16 + quad * 4 + r;           // output dim
            int m = mtile * 16 + l16;                    // token (contiguous store)
            VT[(size_t)n * NTOK + m] = f2bf(acc[r] + bias[n]);
        }
    } else {
        int n = ntile * 16 + l16;
        float bb = bias[n];
        const float sc = (mat == 0) ? 0.25503635559913516f : 1.0f;  // 1/sqrt(32)*log2e
#pragma unroll
        for (int r = 0; r < 4; ++r) {
            int m = mtile * 16 + quad * 4 + r;
            u16 o = f2bf((acc[r] + bb) * sc);
            if (mat == 0) Q[(size_t)m * DIM + n] = o;
            else          K[(size_t)m * DIM + n] = o;
        }
    }
}

// ---------------- kernel 3: single-pass fixed-max attention, register PV ----------------
// grid (128 qtiles, 8 heads), block 256 = 4 waves; wave w handles keys [w*1024,(w+1)*1024)
// S^T = MFMA(A=K,B=Q): C regs hold S^T[key=quad*4+r][query=l16]; after exp these are
// exactly the B-operand of mfma_16x16x16bf16_1k (B[n=l16][k=quad*4+j]) -> PV with no LDS.
__global__ __launch_bounds__(256) void attn_kernel(
    const u16* __restrict__ Q, const u16* __restrict__ K, const u16* __restrict__ VT,
    const u32* __restrict__ adjbits, u16* __restrict__ AO) {
    __shared__ float l_lds[KSPLIT][QTILE];
    __shared__ float o_lds[KSPLIT][QTILE][33];   // [d][query], pad 33 vs bank conflicts

    int tid = threadIdx.x;
    int w = tid >> 6, lane = tid & 63, quad = lane >> 4, l16 = lane & 15;
    int qtile = blockIdx.x, h = blockIdx.y, qbase = qtile * QTILE;
    const float4v zf = {0.f, 0.f, 0.f, 0.f};

    // Q B-fragments for the two 16-query subtiles (n=l16=query, k=quad*8 over HD)
    short8 qf[2];
    qf[0] = *(const short8*)(Q + (size_t)(qbase + l16) * DIM + h * HD + quad * 8);
    qf[1] = *(const short8*)(Q + (size_t)(qbase + 16 + l16) * DIM + h * HD + quad * 8);

    const int kbeg = w * (NTOK / KSPLIT), kend = kbeg + NTOK / KSPLIT;
    float lsum[2] = {0.f, 0.f};
    float4v o[2][2] = {{zf, zf}, {zf, zf}};      // [subtile s][dgroup g] = O^T[d][query]

    const u32* abrow0 = adjbits + (size_t)(qbase + l16) * (NTOK / 32);
    const u32* abrow1 = abrow0 + 16 * (NTOK / 32);

    for (int k0 = kbeg; k0 < kend; k0 += 64) {
        // K A-fragments: 4 chunks of 16 keys (m=l16=key, k=quad*8 over HD)
        short8 kf[4];
#pragma unroll
        for (int c = 0; c < 4; ++c)
            kf[c] = *(const short8*)(K + (size_t)(k0 + c * 16 + l16) * DIM + h * HD + quad * 8);
        // V^T A-fragments for PV: [chunk][dgroup], A[m=d=l16][k=key quad*4+j] (8B loads)
        short4v va[4][2];
#pragma unroll
        for (int c = 0; c < 4; ++c)
#pragma unroll
            for (int g = 0; g < 2; ++g)
                va[c][g] = *(const short4v*)(VT + (size_t)(h * HD + g * 16 + l16) * NTOK
                                             + k0 + c * 16 + quad * 4);
#pragma unroll
        for (int s = 0; s < 2; ++s) {
            uint2 w2 = *(const uint2*)((s ? abrow1 : abrow0) + (k0 >> 5));
#pragma unroll
            for (int c = 0; c < 4; ++c) {
                float4v st = __builtin_amdgcn_mfma_f32_16x16x32_bf16(kf[c], qf[s], zf, 0, 0, 0);
                u32 word = (c < 2) ? w2.x : w2.y;
                int sh = (c & 1) * 16 + quad * 4;
                float e0 = ((word >> (sh + 0)) & 1u) ? __builtin_amdgcn_exp2f(st[0]) : 0.f;
                float e1 = ((word >> (sh + 1)) & 1u) ? __builtin_amdgcn_exp2f(st[1]) : 0.f;
                float e2 = ((word >> (sh + 2)) & 1u) ? __builtin_amdgcn_exp2f(st[2]) : 0.f;
                float e3 = ((word >> (sh + 3)) & 1u) ? __builtin_amdgcn_exp2f(st[3]) : 0.f;
                lsum[s] += (e0 + e1) + (e2 + e3);
                short4v pb;
                pb[0] = (short)f2bf_fast(e0); pb[1] = (short)f2bf_fast(e1);
                pb[2] = (short)f2bf_fast(e2); pb[3] = (short)f2bf_fast(e3);
                o[s][0] = __builtin_amdgcn_mfma_f32_16x16x16bf16_1k(va[c][0], pb, o[s][0], 0, 0, 0);
                o[s][1] = __builtin_amdgcn_mfma_f32_16x16x16bf16_1k(va[c][1], pb, o[s][1], 0, 0, 0);
            }
        }
    }

    // lsum: lanes {l16, l16+16, l16+32, l16+48} hold quad-partials for query l16
#pragma unroll
    for (int s = 0; s < 2; ++s) {
        float v = lsum[s];
        v += __shfl_xor(v, 16, 64);
        v += __shfl_xor(v, 32, 64);
        if (quad == 0) l_lds[w][s * 16 + l16] = v;
    }
    // O^T partials: o[s][g][r] = O^T[d = g*16+quad*4+r][query = s*16+l16]
#pragma unroll
    for (int s = 0; s < 2; ++s)
#pragma unroll
        for (int g = 0; g < 2; ++g)
#pragma unroll
            for (int r = 0; r < 4; ++r)
                o_lds[w][g * 16 + quad * 4 + r][s * 16 + l16] = o[s][g][r];
    __syncthreads();
    // merge KSPLIT partials: 32 queries x 32 dims, threads: d fast (contiguous stores)
#pragma unroll
    for (int i = 0; i < 4; ++i) {
        int e = tid + i * 256;
        int d = e & 31, q = e >> 5;
        float L = l_lds[0][q] + l_lds[1][q] + l_lds[2][q] + l_lds[3][q];
        float val = o_lds[0][d][q] + o_lds[1][d][q] + o_lds[2][d][q] + o_lds[3][d][q];
        AO[(size_t)(qbase + q) * DIM + h * HD + d] = f2bf(val / L);
    }
}

// ---------------- kernel 4: output projection (f32 out) ----------------
__global__ __launch_bounds__(64) void out_gemm(
    const u16* __restrict__ AO, const u16* __restrict__ WTo, const float* __restrict__ bo,
    float* __restrict__ out) {
    int lane = threadIdx.x, quad = lane >> 4, l16 = lane & 15;
    int mtile = blockIdx.x, ntile = blockIdx.y;
    const u16* arow = AO + (size_t)(mtile * 16 + l16) * DIM + quad * 8;
    const u16* brow = WTo + (size_t)(ntile * 16 + l16) * DIM + quad * 8;
    float4v acc = {0.f, 0.f, 0.f, 0.f};
#pragma unroll
    for (int k0 = 0; k0 < DIM; k0 += 32) {
        short8 af = *(const short8*)(arow + k0);
        short8 bf = *(const short8*)(brow + k0);
        acc = __builtin_amdgcn_mfma_f32_16x16x32_bf16(af, bf, acc, 0, 0, 0);
    }
    int n = ntile * 16 + l16;
    float bb = bo[n];
#pragma unroll
    for (int r = 0; r < 4; ++r)
        out[(size_t)(mtile * 16 + quad * 4 + r) * DIM + n] = acc[r] + bb;
}

extern "C" void kernel_launch(void* const* d_in, const int* in_sizes, int n_in,
                              void* d_out, int out_size, void* d_ws, size_t ws_size,
                              hipStream_t stream) {
    const float* x   = (const float*)d_in[0];
    const float* adj = (const float*)d_in[1];
    const float* Wq  = (const float*)d_in[2];
    const float* bq  = (const float*)d_in[3];
    const float* Wk  = (const float*)d_in[4];
    const float* bk  = (const float*)d_in[5];
    const float* Wv  = (const float*)d_in[6];
    const float* bv  = (const float*)d_in[7];
    const float* Wo  = (const float*)d_in[8];
    const float* bo  = (const float*)d_in[9];

    char* ws = (char*)d_ws;
    const size_t MB2 = 1u << 21;
    u16* Q   = (u16*)(ws);              // 2 MB
    u16* K   = (u16*)(ws + 1 * MB2);    // 2 MB
    u16* VT  = (u16*)(ws + 2 * MB2);    // 2 MB (transposed V: [256][4096])
    u16* AO  = (u16*)(ws + 3 * MB2);    // 2 MB
    u32* AB  = (u32*)(ws + 4 * MB2);    // 2 MB adjacency bitmask
    u16* WT  = (u16*)(ws + 5 * MB2);    // 512 KB: WqT,WkT,WvT,WoT
    u16* XB  = (u16*)(ws + 5 * MB2 + (512u << 10));   // 2 MB x in bf16

    x_to_bf16<<<dim3(1024), 256, 0, stream>>>(x, XB);
    transpose_w<<<dim3(256, 4), 256, 0, stream>>>(Wq, Wk, Wv, Wo, WT);
    adj_to_bits<<<dim3(65536), 256, 0, stream>>>(adj, AB);
    qkv_gemm<<<dim3(256, 16, 3), 64, 0, stream>>>(XB, WT, bq, bk, bv, Q, K, VT);
    attn_kernel<<<dim3(128, 8), 256, 0, stream>>>(Q, K, VT, AB, AO);
    out_gemm<<<dim3(256, 16), 64, 0, stream>>>(AO, WT + 3 * 65536, bo, (float*)d_out);
}

// Round 6
// 243.096 us; speedup vs baseline: 1.1118x; 1.1118x over previous
//
#include <hip/hip_runtime.h>
#include <hip/hip_bf16.h>
#include <stdint.h>

#define NTOK 4096
#define DIM  256
#define NH   8
#define HD   32
#define KSPLIT 4     // waves per attention block (K-dim split)
#define QTILE 32     // q-rows per block

typedef __attribute__((ext_vector_type(8))) short short8;
typedef __attribute__((ext_vector_type(4))) short short4v;
typedef __attribute__((ext_vector_type(4))) float float4v;
typedef unsigned short u16;
typedef unsigned int u32;

__device__ __forceinline__ u16 f2bf(float f) {        // RNE (cold paths)
    union { float f; u32 u; } c; c.f = f;
    u32 u = c.u;
    u = u + 0x7FFFu + ((u >> 16) & 1u);
    return (u16)(u >> 16);
}
__device__ __forceinline__ u16 f2bf_fast(float f) {   // round-half-up (hot path)
    union { float f; u32 u; } c; c.f = f;
    return (u16)((c.u + 0x8000u) >> 16);
}

// ---------------- kernel A: x (f32) -> bf16 ----------------
__global__ void x_to_bf16(const float* __restrict__ x, u16* __restrict__ xb) {
    int i = (blockIdx.x * blockDim.x + threadIdx.x) * 4;
    float4 v = *(const float4*)(x + i);
    ushort4 o;
    o.x = f2bf(v.x); o.y = f2bf(v.y); o.z = f2bf(v.z); o.w = f2bf(v.w);
    *(ushort4*)(xb + i) = o;
}

// ---------------- kernel 0: transpose weights (f32 256x256 -> bf16 WT) ----------------
__global__ void transpose_w(const float* __restrict__ Wq, const float* __restrict__ Wk,
                            const float* __restrict__ Wv, const float* __restrict__ Wo,
                            u16* __restrict__ WT) {
    const float* srcs[4] = {Wq, Wk, Wv, Wo};
    const float* W = srcs[blockIdx.y];
    int o = blockIdx.x, i = threadIdx.x;
    WT[blockIdx.y * 65536 + o * 256 + i] = f2bf(W[i * 256 + o]);
}

// ---------------- kernel 1: adj (f32 0/1) -> bitmask via ballot ----------------
__global__ __launch_bounds__(256) void adj_to_bits(const float* __restrict__ adj,
                                                   u32* __restrict__ bits) {
    size_t i = (size_t)blockIdx.x * 256 + threadIdx.x;
    float v = adj[i];
    unsigned long long b = __ballot(v != 0.0f);
    int lane = threadIdx.x & 63;
    if (lane == 0)       bits[i >> 5] = (u32)b;
    else if (lane == 32) bits[i >> 5] = (u32)(b >> 32);
}

// ---------------- kernel 2: QKV projection ----------------
// mat 0 -> Q[m][n] (pre-scaled by 1/sqrt(HD)*log2e), mat 1 -> K[m][n]
// mat 2 -> VT[n][m] via swapped operands: D[n][m] in C-layout -> coalesced store
__global__ __launch_bounds__(64) void qkv_gemm(
    const u16* __restrict__ xb,
    const u16* __restrict__ WT,
    const float* __restrict__ bq, const float* __restrict__ bk, const float* __restrict__ bv,
    u16* __restrict__ Q, u16* __restrict__ K, u16* __restrict__ VT) {
    int lane = threadIdx.x, quad = lane >> 4, l16 = lane & 15;
    int mtile = blockIdx.x, ntile = blockIdx.y, mat = blockIdx.z;
    const float* bias = (mat == 0) ? bq : (mat == 1) ? bk : bv;
    const u16* xrow = xb + (size_t)(mtile * 16 + l16) * DIM + quad * 8;
    const u16* wrow = WT + (size_t)mat * 65536 + (size_t)(ntile * 16 + l16) * DIM + quad * 8;
    const u16* arow = (mat == 2) ? wrow : xrow;   // mat 2: A=W^T rows (n), B=x rows (m)
    const u16* brow = (mat == 2) ? xrow : wrow;
    float4v acc = {0.f, 0.f, 0.f, 0.f};
#pragma unroll
    for (int k0 = 0; k0 < DIM; k0 += 32) {
        short8 af = *(const short8*)(arow + k0);
        short8 bf = *(const short8*)(brow + k0);
        acc = __builtin_amdgcn_mfma_f32_16x16x32_bf16(af, bf, acc, 0, 0, 0);
    }
    if (mat == 2) {
#pragma unroll
        for (int r = 0; r < 4; ++r) {
            int n = ntile * 16 + quad * 4 + r;           // output dim
            int m = mtile * 16 + l16;                    // token (contiguous store)
            VT[(size_t)n * NTOK + m] = f2bf(acc[r] + bias[n]);
        }
    } else {
        int n = ntile * 16 + l16;
        float bb = bias[n];
        const float sc = (mat == 0) ? 0.25503635559913516f : 1.0f;  // 1/sqrt(32)*log2e
#pragma unroll
        for (int r = 0; r < 4; ++r) {
            int m = mtile * 16 + quad * 4 + r;
            u16 o = f2bf((acc[r] + bb) * sc);
            if (mat == 0) Q[(size_t)m * DIM + n] = o;
            else          K[(size_t)m * DIM + n] = o;
        }
    }
}

// ---------------- kernel 3: single-pass fixed-max attention ----------------
// grid (128 qtiles, 8 heads), block 256 = 4 waves; wave w handles keys [w*1024,(w+1)*1024)
// S^T = MFMA(A=K,B=Q): lane holds keys quad*4..quad*4+3 for query l16 -> pack short4 ->
// ONE ds_write_b64 per chunk; read back b128 as K=32 P A-frags; PV with VT B-frags.
// LDS ops per 64-key iter: 8x write_b64 + 4x read_b128 (vs 32x write_b16 + 4x read in R4).
__global__ __launch_bounds__(256, 4) void attn_kernel(
    const u16* __restrict__ Q, const u16* __restrict__ K, const u16* __restrict__ VT,
    const u32* __restrict__ adjbits, u16* __restrict__ AO) {
    __shared__ float l_lds[KSPLIT][QTILE];
    __shared__ float o_lds[KSPLIT][QTILE][HD];                 // [q][d], 16 KB
    __shared__ __align__(16) u16 plds[KSPLIT][QTILE][72];      // [query][key], stride 72

    int tid = threadIdx.x;
    int w = tid >> 6, lane = tid & 63, quad = lane >> 4, l16 = lane & 15;
    int qtile = blockIdx.x, h = blockIdx.y, qbase = qtile * QTILE;
    const float4v zf = {0.f, 0.f, 0.f, 0.f};

    // Q B-fragments (n=l16=query, k=quad*8 over HD)
    short8 qf[2];
    qf[0] = *(const short8*)(Q + (size_t)(qbase + l16) * DIM + h * HD + quad * 8);
    qf[1] = *(const short8*)(Q + (size_t)(qbase + 16 + l16) * DIM + h * HD + quad * 8);

    const int kbeg = w * (NTOK / KSPLIT), kend = kbeg + NTOK / KSPLIT;
    float lsum[2] = {0.f, 0.f};
    float4v o[2][2] = {{zf, zf}, {zf, zf}};   // [subtile s][dgroup g]: O[q=quad*4+r][d=g*16+l16]

    const u32* abrow0 = adjbits + (size_t)(qbase + l16) * (NTOK / 32);
    const u32* abrow1 = abrow0 + 16 * (NTOK / 32);

    for (int k0 = kbeg; k0 < kend; k0 += 64) {
        // K A-fragments: 4 chunks of 16 keys (m=key l16, k=quad*8 over HD)
        short8 kf[4];
#pragma unroll
        for (int c = 0; c < 4; ++c)
            kf[c] = *(const short8*)(K + (size_t)(k0 + c * 16 + l16) * DIM + h * HD + quad * 8);
        // V^T B-fragments: [cc=32-key chunk][g=dgroup]: B[k=quad*8+j][n=d g*16+l16], 16B
        short8 vf[2][2];
#pragma unroll
        for (int cc = 0; cc < 2; ++cc)
#pragma unroll
            for (int g = 0; g < 2; ++g)
                vf[cc][g] = *(const short8*)(VT + (size_t)(h * HD + g * 16 + l16) * NTOK
                                             + k0 + cc * 32 + quad * 8);
        uint2 w2s[2];
        w2s[0] = *(const uint2*)(abrow0 + (k0 >> 5));
        w2s[1] = *(const uint2*)(abrow1 + (k0 >> 5));

        // all 8 QK MFMAs first (independent) -> st[s][c][r] = S^T[key c*16+quad*4+r][query l16]
        float4v st[2][4];
#pragma unroll
        for (int s = 0; s < 2; ++s)
#pragma unroll
            for (int c = 0; c < 4; ++c)
                st[s][c] = __builtin_amdgcn_mfma_f32_16x16x32_bf16(kf[c], qf[s], zf, 0, 0, 0);

#pragma unroll
        for (int s = 0; s < 2; ++s) {
#pragma unroll
            for (int c = 0; c < 4; ++c) {
                u32 word = (c < 2) ? w2s[s].x : w2s[s].y;
                int sh = (c & 1) * 16 + quad * 4;
                float e0 = ((word >> (sh + 0)) & 1u) ? __builtin_amdgcn_exp2f(st[s][c][0]) : 0.f;
                float e1 = ((word >> (sh + 1)) & 1u) ? __builtin_amdgcn_exp2f(st[s][c][1]) : 0.f;
                float e2 = ((word >> (sh + 2)) & 1u) ? __builtin_amdgcn_exp2f(st[s][c][2]) : 0.f;
                float e3 = ((word >> (sh + 3)) & 1u) ? __builtin_amdgcn_exp2f(st[s][c][3]) : 0.f;
                lsum[s] += (e0 + e1) + (e2 + e3);
                short4v pb;
                pb[0] = (short)f2bf_fast(e0); pb[1] = (short)f2bf_fast(e1);
                pb[2] = (short)f2bf_fast(e2); pb[3] = (short)f2bf_fast(e3);
                *(short4v*)(&plds[w][s * 16 + l16][c * 16 + quad * 4]) = pb;  // ds_write_b64
            }
            // P A-frags: A[m=query l16][k=key quad*8+j] per 32-key chunk (b128)
            short8 pa0 = *(const short8*)(&plds[w][s * 16 + l16][0  + quad * 8]);
            short8 pa1 = *(const short8*)(&plds[w][s * 16 + l16][32 + quad * 8]);
            o[s][0] = __builtin_amdgcn_mfma_f32_16x16x32_bf16(pa0, vf[0][0], o[s][0], 0, 0, 0);
            o[s][1] = __builtin_amdgcn_mfma_f32_16x16x32_bf16(pa0, vf[0][1], o[s][1], 0, 0, 0);
            o[s][0] = __builtin_amdgcn_mfma_f32_16x16x32_bf16(pa1, vf[1][0], o[s][0], 0, 0, 0);
            o[s][1] = __builtin_amdgcn_mfma_f32_16x16x32_bf16(pa1, vf[1][1], o[s][1], 0, 0, 0);
        }
    }

    // lsum: quads hold key-partials for query l16 -> reduce across quads
#pragma unroll
    for (int s = 0; s < 2; ++s) {
        float v = lsum[s];
        v += __shfl_xor(v, 16, 64);
        v += __shfl_xor(v, 32, 64);
        if (quad == 0) l_lds[w][s * 16 + l16] = v;
    }
    // O partials: o[s][g][r] = O[q=s*16+quad*4+r][d=g*16+l16]
#pragma unroll
    for (int s = 0; s < 2; ++s)
#pragma unroll
        for (int g = 0; g < 2; ++g)
#pragma unroll
            for (int r = 0; r < 4; ++r)
                o_lds[w][s * 16 + quad * 4 + r][g * 16 + l16] = o[s][g][r];
    __syncthreads();
    // merge KSPLIT partials: 32 queries x 32 dims, d fast (contiguous stores)
#pragma unroll
    for (int i = 0; i < 4; ++i) {
        int e = tid + i * 256;
        int d = e & 31, q = e >> 5;
        float L = l_lds[0][q] + l_lds[1][q] + l_lds[2][q] + l_lds[3][q];
        float val = o_lds[0][q][d] + o_lds[1][q][d] + o_lds[2][q][d] + o_lds[3][q][d];
        AO[(size_t)(qbase + q) * DIM + h * HD + d] = f2bf(val / L);
    }
}

// ---------------- kernel 4: output projection (f32 out) ----------------
__global__ __launch_bounds__(64) void out_gemm(
    const u16* __restrict__ AO, const u16* __restrict__ WTo, const float* __restrict__ bo,
    float* __restrict__ out) {
    int lane = threadIdx.x, quad = lane >> 4, l16 = lane & 15;
    int mtile = blockIdx.x, ntile = blockIdx.y;
    const u16* arow = AO + (size_t)(mtile * 16 + l16) * DIM + quad * 8;
    const u16* brow = WTo + (size_t)(ntile * 16 + l16) * DIM + quad * 8;
    float4v acc = {0.f, 0.f, 0.f, 0.f};
#pragma unroll
    for (int k0 = 0; k0 < DIM; k0 += 32) {
        short8 af = *(const short8*)(arow + k0);
        short8 bf = *(const short8*)(brow + k0);
        acc = __builtin_amdgcn_mfma_f32_16x16x32_bf16(af, bf, acc, 0, 0, 0);
    }
    int n = ntile * 16 + l16;
    float bb = bo[n];
#pragma unroll
    for (int r = 0; r < 4; ++r)
        out[(size_t)(mtile * 16 + quad * 4 + r) * DIM + n] = acc[r] + bb;
}

extern "C" void kernel_launch(void* const* d_in, const int* in_sizes, int n_in,
                              void* d_out, int out_size, void* d_ws, size_t ws_size,
                              hipStream_t stream) {
    const float* x   = (const float*)d_in[0];
    const float* adj = (const float*)d_in[1];
    const float* Wq  = (const float*)d_in[2];
    const float* bq  = (const float*)d_in[3];
    const float* Wk  = (const float*)d_in[4];
    const float* bk  = (const float*)d_in[5];
    const float* Wv  = (const float*)d_in[6];
    const float* bv  = (const float*)d_in[7];
    const float* Wo  = (const float*)d_in[8];
    const float* bo  = (const float*)d_in[9];

    char* ws = (char*)d_ws;
    const size_t MB2 = 1u << 21;
    u16* Q   = (u16*)(ws);              // 2 MB
    u16* K   = (u16*)(ws + 1 * MB2);    // 2 MB
    u16* VT  = (u16*)(ws + 2 * MB2);    // 2 MB (transposed V: [256][4096])
    u16* AO  = (u16*)(ws + 3 * MB2);    // 2 MB
    u32* AB  = (u32*)(ws + 4 * MB2);    // 2 MB adjacency bitmask
    u16* WT  = (u16*)(ws + 5 * MB2);    // 512 KB: WqT,WkT,WvT,WoT
    u16* XB  = (u16*)(ws + 5 * MB2 + (512u << 10));   // 2 MB x in bf16

    x_to_bf16<<<dim3(1024), 256, 0, stream>>>(x, XB);
    transpose_w<<<dim3(256, 4), 256, 0, stream>>>(Wq, Wk, Wv, Wo, WT);
    adj_to_bits<<<dim3(65536), 256, 0, stream>>>(adj, AB);
    qkv_gemm<<<dim3(256, 16, 3), 64, 0, stream>>>(XB, WT, bq, bk, bv, Q, K, VT);
    attn_kernel<<<dim3(128, 8), 256, 0, stream>>>(Q, K, VT, AB, AO);
    out_gemm<<<dim3(256, 16), 64, 0, stream>>>(AO, WT + 3 * 65536, bo, (float*)d_out);
}